// Round 2
// baseline (406.285 us; speedup 1.0000x reference)
//
#include <hip/hip_runtime.h>
#include <hip/hip_bf16.h>

#define NB 8
#define NS 4096
#define ND 256
#define TQ 128
#define TK 64
#define NTHR 512
#define LDC 264   // 256 + 8 shorts pad: row stride 528B -> 2-way bank alias (free)

typedef __attribute__((ext_vector_type(8))) short short8;
typedef __attribute__((ext_vector_type(4))) short short4v;
typedef __attribute__((ext_vector_type(4))) float f32x4;

__device__ __forceinline__ short f2bf(float f) {
  unsigned u = __builtin_bit_cast(unsigned, f);
  u += 0x7FFFu + ((u >> 16) & 1u);   // RNE
  return (short)(u >> 16);
}

__global__ void cvt_bf16_kernel(const float* __restrict__ x, short* __restrict__ xbf) {
  size_t i = ((size_t)blockIdx.x * 256 + threadIdx.x) * 4;
  f32x4 v = *(const f32x4*)(x + i);
  short4v o;
  #pragma unroll
  for (int j = 0; j < 4; ++j) o[j] = f2bf(v[j]);
  *(short4v*)(xbf + i) = o;
}

__launch_bounds__(NTHR, 2)
__global__ void attn_colsum_kernel(const float* __restrict__ x,
                                   const float* __restrict__ mask,
                                   const short* __restrict__ xbf,
                                   float* __restrict__ w) {
  __shared__ short Xs[TK][LDC];
  const int bid  = blockIdx.x;
  const int b    = bid & 7;        // XCD swizzle: each XCD mostly sees one batch
  const int qt   = bid >> 3;       // 0..31
  const int q0   = qt * TQ;
  const int tid  = threadIdx.x;
  const int wave = tid >> 6;
  const int lane = tid & 63;
  const int lr   = lane & 15;
  const int lg   = lane >> 4;
  const float SCALE = 0.0625f;     // 1/sqrt(256)

  const size_t bbase = (size_t)b * NS * ND;

  // A-operand (Q = x*mask) fragments, held in registers for the whole block.
  // mfma_f32_16x16x32_bf16 A layout: m = lane%16, k = 8*(lane/16) + [0..7]
  short8 a_frag[8];
  {
    const int row = q0 + wave * 16 + lr;
    const float* xr = x + bbase + (size_t)row * ND;
    const float* mr = mask + bbase + (size_t)row * ND;
    #pragma unroll
    for (int dblk = 0; dblk < 8; ++dblk) {
      const int d0 = dblk * 32 + lg * 8;
      f32x4 x0 = *(const f32x4*)(xr + d0);
      f32x4 x1 = *(const f32x4*)(xr + d0 + 4);
      f32x4 m0 = *(const f32x4*)(mr + d0);
      f32x4 m1 = *(const f32x4*)(mr + d0 + 4);
      short8 a;
      #pragma unroll
      for (int j = 0; j < 4; ++j) a[j] = f2bf(x0[j] * m0[j]);
      #pragma unroll
      for (int j = 0; j < 4; ++j) a[4 + j] = f2bf(x1[j] * m1[j]);
      a_frag[dblk] = a;
    }
  }

  float l_part[4] = {0.f, 0.f, 0.f, 0.f};
  float rl[4] = {0.f, 0.f, 0.f, 0.f};

  for (int pass = 0; pass < 2; ++pass) {
    if (pass == 1) {
      // finish row denominators: reduce lane partials across the 16 lanes
      // sharing each row (C/D layout: row = 4*(lane>>4)+i, col = lane&15)
      #pragma unroll
      for (int i = 0; i < 4; ++i) {
        float v = l_part[i];
        v += __shfl_xor(v, 1);
        v += __shfl_xor(v, 2);
        v += __shfl_xor(v, 4);
        v += __shfl_xor(v, 8);
        rl[i] = 1.0f / v;
      }
    }
    for (int t = 0; t < NS / TK; ++t) {
      const int k0 = t * TK;
      // ---- stage K-tile (x[b, k0:k0+64, :]) into LDS as bf16 ----
      if (xbf) {
        const short* src = xbf + bbase + (size_t)k0 * ND;
        #pragma unroll
        for (int r = 0; r < (TK * ND / 8) / NTHR; ++r) {   // 4 iters
          int idx = tid + NTHR * r;
          int row = idx >> 5;
          int c = (idx & 31) * 8;
          *(short8*)&Xs[row][c] = *(const short8*)&src[row * ND + c];
        }
      } else {
        const float* src = x + bbase + (size_t)k0 * ND;
        #pragma unroll
        for (int r = 0; r < (TK * ND / 4) / NTHR; ++r) {   // 8 iters
          int idx = tid + NTHR * r;
          int row = idx >> 6;
          int c = (idx & 63) * 4;
          f32x4 v = *(const f32x4*)&src[row * ND + c];
          short4v o;
          #pragma unroll
          for (int j = 0; j < 4; ++j) o[j] = f2bf(v[j]);
          *(short4v*)&Xs[row][c] = o;
        }
      }
      __syncthreads();

      // ---- 16q x 64k scores for this wave via MFMA ----
      // B layout: n = lane%16 (tile row of X), k = 8*(lane/16)+[0..7] (d)
      f32x4 acc[4];
      #pragma unroll
      for (int n = 0; n < 4; ++n) acc[n] = f32x4{0.f, 0.f, 0.f, 0.f};
      #pragma unroll
      for (int dblk = 0; dblk < 8; ++dblk) {
        #pragma unroll
        for (int n = 0; n < 4; ++n) {
          short8 bf = *(const short8*)&Xs[n * 16 + lr][dblk * 32 + lg * 8];
          acc[n] = __builtin_amdgcn_mfma_f32_16x16x32_bf16(a_frag[dblk], bf, acc[n], 0, 0, 0);
        }
      }

      if (pass == 0) {
        // accumulate per-lane partial row sums of exp(s)
        #pragma unroll
        for (int n = 0; n < 4; ++n)
          #pragma unroll
          for (int i = 0; i < 4; ++i)
            l_part[i] += __expf(acc[n][i] * SCALE);
      } else {
        // normalized column sums -> w
        #pragma unroll
        for (int n = 0; n < 4; ++n) {
          float cs = 0.f;
          #pragma unroll
          for (int i = 0; i < 4; ++i)
            cs += __expf(acc[n][i] * SCALE) * rl[i];
          cs += __shfl_xor(cs, 16);   // sum over the wave's 16 rows
          cs += __shfl_xor(cs, 32);
          if (lg == 0)
            atomicAdd(&w[(size_t)b * NS + k0 + n * 16 + lr], cs);
        }
      }
      __syncthreads();
    }
  }
}

__global__ void out_kernel(const float* __restrict__ x, const float* __restrict__ w,
                           float* __restrict__ out) {
  const int b  = blockIdx.x & 7;
  const int kc = blockIdx.x >> 3;   // 0..31, 128 k each
  const int d  = threadIdx.x;       // 256
  const int k0 = kc * 128;
  const float* xb = x + ((size_t)b * NS + k0) * ND;
  const float* wb = w + (size_t)b * NS + k0;
  float acc = 0.f;
  #pragma unroll 4
  for (int k = 0; k < 128; ++k)
    acc += wb[k] * xb[(size_t)k * ND + d];
  atomicAdd(&out[b * ND + d], acc);
}

extern "C" void kernel_launch(void* const* d_in, const int* in_sizes, int n_in,
                              void* d_out, int out_size, void* d_ws, size_t ws_size,
                              hipStream_t stream) {
  const float* x    = (const float*)d_in[0];
  const float* mask = (const float*)d_in[1];
  float* w = (float*)d_ws;
  const size_t W_BYTES   = (size_t)NB * NS * sizeof(float);        // 128 KB
  const size_t XBF_BYTES = (size_t)NB * NS * ND * sizeof(short);   // 16 MB
  short* xbf = nullptr;
  if (ws_size >= W_BYTES + XBF_BYTES)
    xbf = (short*)((char*)d_ws + W_BYTES);

  hipMemsetAsync(d_ws, 0, W_BYTES, stream);
  hipMemsetAsync(d_out, 0, (size_t)out_size * sizeof(float), stream);

  if (xbf)
    cvt_bf16_kernel<<<(NB * NS * ND / 4) / 256, 256, 0, stream>>>(x, xbf);

  attn_colsum_kernel<<<NB * (NS / TQ), NTHR, 0, stream>>>(x, mask, xbf, w);
  out_kernel<<<NB * (NS / 128), 256, 0, stream>>>(x, w, (float*)d_out);
}

// Round 3
// 363.858 us; speedup vs baseline: 1.1166x; 1.1166x over previous
//
#include <hip/hip_runtime.h>
#include <hip/hip_bf16.h>

#define NB 8
#define NS 4096
#define ND 256
#define TQ 128          // q rows per block = 2 M-waves * 64
#define TK 64           // k cols per tile
#define NTHR 512        // 8 waves = 2(M) x 4(N)
#define NTILES (NS / TK)

typedef __attribute__((ext_vector_type(8))) short short8;
typedef __attribute__((ext_vector_type(4))) float f32x4;

__device__ __forceinline__ short f2bf(float f) {
  unsigned u = __builtin_bit_cast(unsigned, f);
  u += 0x7FFFu + ((u >> 16) & 1u);   // RNE
  return (short)(u >> 16);
}

// Pre-swizzled bf16 cast: xbf[row][c] (16B chunks c=0..31) = x[row][c ^ (row&7)].
// Staging then copies rows LINEARLY into LDS (global_load_lds requirement),
// and the ds_read side applies the same XOR -> conflict-free (rule-21 pattern).
__global__ void cvt_swz_kernel(const float* __restrict__ x, short* __restrict__ xbf) {
  int gid = blockIdx.x * 256 + threadIdx.x;   // one thread per 16B chunk
  int row = gid >> 5;
  int c   = gid & 31;
  int cs  = c ^ (row & 7);
  const float* src = x + (size_t)row * ND + cs * 8;
  f32x4 v0 = *(const f32x4*)src;
  f32x4 v1 = *(const f32x4*)(src + 4);
  short8 o;
  #pragma unroll
  for (int j = 0; j < 4; ++j) o[j] = f2bf(v0[j]);
  #pragma unroll
  for (int j = 0; j < 4; ++j) o[4 + j] = f2bf(v1[j]);
  *(short8*)(xbf + (size_t)row * ND + c * 8) = o;
}

__launch_bounds__(NTHR, 2)
__global__ void attn_colsum_kernel(const float* __restrict__ x,
                                   const float* __restrict__ mask,
                                   const short* __restrict__ xbf,
                                   float* __restrict__ w) {
  __shared__ short Xs[2][TK][ND];     // 2 x 32KB, linear 512B rows (no pad!)
  __shared__ float Lred[2][64][4];    // cross-wave denominator reduce
  const int bid  = blockIdx.x;
  const int b    = bid & 7;           // XCD swizzle
  const int qt   = bid >> 3;
  const int q0   = qt * TQ;
  const int tid  = threadIdx.x;
  const int wid  = tid >> 6;
  const int lane = tid & 63;
  const int mi   = wid >> 2;          // 0..1 : which 64-q-row group
  const int ni   = wid & 3;           // 0..3 : which 16-col slice of the k-tile
  const int lr   = lane & 15;
  const int lg   = lane >> 4;
  const float SCALE = 0.0625f;

  const size_t bbase = (size_t)b * NS * ND;
  const short* xb = xbf ? xbf + bbase : nullptr;

  // ---- A fragments: 4 m-sets x 8 dblk, held in registers all kernel ----
  // A layout (16x16x32): m = lane%16, k = 8*(lane/16)+[0..7]
  short8 a_frag[4][8];
  #pragma unroll
  for (int m = 0; m < 4; ++m) {
    const int row = q0 + mi * 64 + m * 16 + lr;
    const float* xr = x + bbase + (size_t)row * ND;
    const float* mr = mask + bbase + (size_t)row * ND;
    #pragma unroll
    for (int dblk = 0; dblk < 8; ++dblk) {
      const int d0 = dblk * 32 + lg * 8;
      f32x4 x0 = *(const f32x4*)(xr + d0);
      f32x4 x1 = *(const f32x4*)(xr + d0 + 4);
      f32x4 m0 = *(const f32x4*)(mr + d0);
      f32x4 m1 = *(const f32x4*)(mr + d0 + 4);
      short8 a;
      #pragma unroll
      for (int j = 0; j < 4; ++j) a[j] = f2bf(x0[j] * m0[j]);
      #pragma unroll
      for (int j = 0; j < 4; ++j) a[4 + j] = f2bf(x1[j] * m1[j]);
      a_frag[m][dblk] = a;
    }
  }

  float l_part[4][4];
  float rl[4][4];
  #pragma unroll
  for (int m = 0; m < 4; ++m)
    #pragma unroll
    for (int i = 0; i < 4; ++i) l_part[m][i] = 0.f;

  // STAGE: copy tile t (64 rows x 512B) linearly into Xs[buf].
  auto STAGE = [&](int buf, int t) {
    const int k0 = t * TK;
    if (xb) {
      #pragma unroll
      for (int c = 0; c < 4; ++c) {
        const int blkid = wid * 4 + c;                 // 0..31, 1KB each
        const int rowg  = k0 + blkid * 2 + (lane >> 5);
        const short* gp = xb + (size_t)rowg * ND + (lane & 31) * 8;
        char* lp = (char*)&Xs[buf][0][0] + blkid * 1024;  // wave-uniform
        __builtin_amdgcn_global_load_lds(
            (const __attribute__((address_space(1))) void*)gp,
            (__attribute__((address_space(3))) void*)lp, 16, 0, 0);
      }
    } else {
      // fallback: reg-stage fp32->bf16 with swizzled writes
      #pragma unroll
      for (int r = 0; r < 4; ++r) {
        int idx = tid + NTHR * r;          // 0..2047 chunks
        int row = idx >> 5;
        int c   = idx & 31;
        const float* src = x + bbase + (size_t)(k0 + row) * ND + ((c ^ (row & 7)) * 8);
        f32x4 v0 = *(const f32x4*)src;
        f32x4 v1 = *(const f32x4*)(src + 4);
        short8 o;
        #pragma unroll
        for (int j = 0; j < 4; ++j) o[j] = f2bf(v0[j]);
        #pragma unroll
        for (int j = 0; j < 4; ++j) o[4 + j] = f2bf(v1[j]);
        *(short8*)&Xs[buf][row][c * 8] = o;
      }
    }
  };

  for (int pass = 0; pass < 2; ++pass) {
    if (pass == 1) {
      // ---- row denominators: reduce over cols (lr lanes), then over the 4 N-waves ----
      #pragma unroll
      for (int m = 0; m < 4; ++m)
        #pragma unroll
        for (int i = 0; i < 4; ++i) {
          float v = l_part[m][i];
          v += __shfl_xor(v, 1);
          v += __shfl_xor(v, 2);
          v += __shfl_xor(v, 4);
          v += __shfl_xor(v, 8);
          l_part[m][i] = v;
        }
      if (lr == 0) {
        #pragma unroll
        for (int m = 0; m < 4; ++m)
          #pragma unroll
          for (int i = 0; i < 4; ++i)
            Lred[mi][m * 16 + lg * 4 + i][ni] = l_part[m][i];
      }
      __syncthreads();
      #pragma unroll
      for (int m = 0; m < 4; ++m)
        #pragma unroll
        for (int i = 0; i < 4; ++i) {
          const float* p = Lred[mi][m * 16 + lg * 4 + i];
          rl[m][i] = 1.0f / (p[0] + p[1] + p[2] + p[3]);
        }
    }

    STAGE(0, 0);
    __syncthreads();                       // drains vmcnt -> tile 0 resident
    int cur = 0;
    for (int t = 0; t < NTILES; ++t) {
      if (t + 1 < NTILES) STAGE(cur ^ 1, t + 1);   // prefetch next tile

      // ---- B fragments from LDS (swizzled read) ----
      // B layout: col = lane%16 -> Xs row = ni*16+lr ; k = 8*(lane/16)+[0..7]
      const int brow = ni * 16 + lr;
      const char* rbase = (const char*)&Xs[cur][brow][0];
      short8 bfrag[8];
      #pragma unroll
      for (int dblk = 0; dblk < 8; ++dblk) {
        const int chunk = (dblk * 4 + lg) ^ (lr & 7);
        bfrag[dblk] = *(const short8*)(rbase + chunk * 16);
      }

      f32x4 acc[4];
      #pragma unroll
      for (int m = 0; m < 4; ++m) acc[m] = f32x4{0.f, 0.f, 0.f, 0.f};
      #pragma unroll
      for (int m = 0; m < 4; ++m)
        #pragma unroll
        for (int dblk = 0; dblk < 8; ++dblk)
          acc[m] = __builtin_amdgcn_mfma_f32_16x16x32_bf16(a_frag[m][dblk], bfrag[dblk], acc[m], 0, 0, 0);

      if (pass == 0) {
        #pragma unroll
        for (int m = 0; m < 4; ++m)
          #pragma unroll
          for (int i = 0; i < 4; ++i)
            l_part[m][i] += __expf(acc[m][i] * SCALE);
      } else {
        float cs = 0.f;
        #pragma unroll
        for (int m = 0; m < 4; ++m)
          #pragma unroll
          for (int i = 0; i < 4; ++i)
            cs += __expf(acc[m][i] * SCALE) * rl[m][i];
        cs += __shfl_xor(cs, 16);    // sum over the wave's 64 q-rows (lg groups)
        cs += __shfl_xor(cs, 32);
        if (lg == 0)
          atomicAdd(&w[(size_t)b * NS + t * TK + ni * 16 + lr], cs);
      }
      __syncthreads();               // also drains prefetch vmcnt
      cur ^= 1;
    }
  }
}

__global__ void out_kernel(const float* __restrict__ x, const float* __restrict__ w,
                           float* __restrict__ out) {
  const int b  = blockIdx.x & 7;
  const int kc = blockIdx.x >> 3;
  const int d  = threadIdx.x;
  const int k0 = kc * 128;
  const float* xbp = x + ((size_t)b * NS + k0) * ND;
  const float* wb  = w + (size_t)b * NS + k0;
  float acc = 0.f;
  #pragma unroll 4
  for (int k = 0; k < 128; ++k)
    acc += wb[k] * xbp[(size_t)k * ND + d];
  atomicAdd(&out[b * ND + d], acc);
}

extern "C" void kernel_launch(void* const* d_in, const int* in_sizes, int n_in,
                              void* d_out, int out_size, void* d_ws, size_t ws_size,
                              hipStream_t stream) {
  const float* x    = (const float*)d_in[0];
  const float* mask = (const float*)d_in[1];
  float* w = (float*)d_ws;
  const size_t W_BYTES   = (size_t)NB * NS * sizeof(float);        // 128 KB
  const size_t XBF_BYTES = (size_t)NB * NS * ND * sizeof(short);   // 16 MB
  short* xbf = nullptr;
  if (ws_size >= W_BYTES + XBF_BYTES)
    xbf = (short*)((char*)d_ws + W_BYTES);

  hipMemsetAsync(d_ws, 0, W_BYTES, stream);
  hipMemsetAsync(d_out, 0, (size_t)out_size * sizeof(float), stream);

  if (xbf)
    cvt_swz_kernel<<<(NB * NS * 32) / 256, 256, 0, stream>>>(x, xbf);

  attn_colsum_kernel<<<NB * (NS / TQ), NTHR, 0, stream>>>(x, mask, xbf, w);
  out_kernel<<<NB * (NS / 128), 256, 0, stream>>>(x, w, (float*)d_out);
}

// Round 4
// 320.342 us; speedup vs baseline: 1.2683x; 1.1358x over previous
//
#include <hip/hip_runtime.h>
#include <hip/hip_bf16.h>

#define NB 8
#define NS 4096
#define ND 256
#define TQ 64           // q rows per block; each wave holds all 64 in registers
#define TK 64           // k cols per tile
#define NTHR 256        // 4 waves, pure N-split (16 cols each)
#define NTILES (NS / TK)

typedef __attribute__((ext_vector_type(8))) short short8;
typedef __attribute__((ext_vector_type(4))) float f32x4;

__device__ __forceinline__ short f2bf(float f) {
  unsigned u = __builtin_bit_cast(unsigned, f);
  u += 0x7FFFu + ((u >> 16) & 1u);   // RNE
  return (short)(u >> 16);
}

// Pre-swizzled bf16 cast: xbf[row][c] (16B chunks c=0..31) = x[row][c ^ (row&7)].
// Staging copies rows LINEARLY into LDS (global_load_lds requirement); the
// ds_read side applies the same XOR -> rule-21 both-sides swizzle.
__global__ void cvt_swz_kernel(const float* __restrict__ x, short* __restrict__ xbf) {
  int gid = blockIdx.x * 256 + threadIdx.x;   // one thread per 16B chunk
  int row = gid >> 5;
  int c   = gid & 31;
  int cs  = c ^ (row & 7);
  const float* src = x + (size_t)row * ND + cs * 8;
  f32x4 v0 = *(const f32x4*)src;
  f32x4 v1 = *(const f32x4*)(src + 4);
  short8 o;
  #pragma unroll
  for (int j = 0; j < 4; ++j) o[j] = f2bf(v0[j]);
  #pragma unroll
  for (int j = 0; j < 4; ++j) o[4 + j] = f2bf(v1[j]);
  *(short8*)(xbf + (size_t)row * ND + c * 8) = o;
}

__launch_bounds__(NTHR, 2)
__global__ void attn_colsum_kernel(const float* __restrict__ x,
                                   const float* __restrict__ mask,
                                   const short* __restrict__ xbf,
                                   float* __restrict__ w) {
  __shared__ short Xs[2][TK][ND];     // 2 x 32KB, linear 512B rows
  __shared__ float Lred[TQ][4];       // cross-wave denominator reduce (1KB)
  const int bid  = blockIdx.x;
  const int b    = bid & 7;           // XCD swizzle: one batch per XCD
  const int qt   = bid >> 3;          // 0..63
  const int q0   = qt * TQ;
  const int tid  = threadIdx.x;
  const int wid  = tid >> 6;          // 0..3 == ni (col slice)
  const int lane = tid & 63;
  const int lr   = lane & 15;
  const int lg   = lane >> 4;
  const float SCALE = 0.0625f;        // 1/sqrt(256)

  const size_t bbase = (size_t)b * NS * ND;
  const short* xb = xbf ? xbf + bbase : nullptr;

  // ---- A fragments: 4 m-sets x 8 dblk, in registers (AGPR side) all kernel ----
  // A layout (16x16x32): m-row = lane%16, k = 8*(lane/16)+[0..7]
  short8 a_frag[4][8];
  #pragma unroll
  for (int m = 0; m < 4; ++m) {
    const int row = q0 + m * 16 + lr;
    const float* xr = x + bbase + (size_t)row * ND;
    const float* mr = mask + bbase + (size_t)row * ND;
    #pragma unroll
    for (int dblk = 0; dblk < 8; ++dblk) {
      const int d0 = dblk * 32 + lg * 8;
      f32x4 x0 = *(const f32x4*)(xr + d0);
      f32x4 x1 = *(const f32x4*)(xr + d0 + 4);
      f32x4 m0 = *(const f32x4*)(mr + d0);
      f32x4 m1 = *(const f32x4*)(mr + d0 + 4);
      short8 a;
      #pragma unroll
      for (int j = 0; j < 4; ++j) a[j] = f2bf(x0[j] * m0[j]);
      #pragma unroll
      for (int j = 0; j < 4; ++j) a[4 + j] = f2bf(x1[j] * m1[j]);
      a_frag[m][dblk] = a;
    }
  }

  // ---- hoisted addresses ----
  // staging: 8 chunks of 1KB per thread-group; per-thread global base
  const short* gbase = xb ? xb + (size_t)(wid * 16 + (lane >> 5)) * ND + (lane & 31) * 8
                          : nullptr;
  char* lbase = (char*)&Xs[0][0][0] + wid * 8192;
  // ds_read byte offsets (swizzled) for the 8 dblk fragments
  int dsoff[8];
  #pragma unroll
  for (int dblk = 0; dblk < 8; ++dblk)
    dsoff[dblk] = (((dblk * 4 + lg) ^ (lr & 7)) << 4);
  const char* rbase = (const char*)&Xs[0][wid * 16 + lr][0];

  float l_part[4][4];
  float rl[4][4];
  #pragma unroll
  for (int m = 0; m < 4; ++m)
    #pragma unroll
    for (int i = 0; i < 4; ++i) l_part[m][i] = 0.f;

  auto STAGE = [&](int buf, int t) {
    if (xb) {
      const short* gp = gbase + (size_t)t * TK * ND;
      char* lp = lbase + buf * 32768;
      #pragma unroll
      for (int c = 0; c < 8; ++c) {
        __builtin_amdgcn_global_load_lds(
            (const __attribute__((address_space(1))) void*)(gp + c * 2 * ND),
            (__attribute__((address_space(3))) void*)(lp + c * 1024), 16, 0, 0);
      }
    } else {
      const int k0 = t * TK;
      #pragma unroll
      for (int r = 0; r < 8; ++r) {
        int idx = tid + NTHR * r;          // 0..2047 chunks
        int row = idx >> 5;
        int c   = idx & 31;
        const float* src = x + bbase + (size_t)(k0 + row) * ND + ((c ^ (row & 7)) * 8);
        f32x4 v0 = *(const f32x4*)src;
        f32x4 v1 = *(const f32x4*)(src + 4);
        short8 o;
        #pragma unroll
        for (int j = 0; j < 4; ++j) o[j] = f2bf(v0[j]);
        #pragma unroll
        for (int j = 0; j < 4; ++j) o[4 + j] = f2bf(v1[j]);
        *(short8*)&Xs[buf][row][c * 8] = o;
      }
    }
  };

  for (int pass = 0; pass < 2; ++pass) {
    if (pass == 1) {
      // row denominators: reduce over the 16 col-lanes, then over the 4 N-waves
      #pragma unroll
      for (int m = 0; m < 4; ++m)
        #pragma unroll
        for (int i = 0; i < 4; ++i) {
          float v = l_part[m][i];
          v += __shfl_xor(v, 1);
          v += __shfl_xor(v, 2);
          v += __shfl_xor(v, 4);
          v += __shfl_xor(v, 8);
          l_part[m][i] = v;
        }
      if (lr == 0) {
        #pragma unroll
        for (int m = 0; m < 4; ++m)
          #pragma unroll
          for (int i = 0; i < 4; ++i)
            Lred[m * 16 + lg * 4 + i][wid] = l_part[m][i];
      }
      __syncthreads();
      #pragma unroll
      for (int m = 0; m < 4; ++m)
        #pragma unroll
        for (int i = 0; i < 4; ++i) {
          const float* p = Lred[m * 16 + lg * 4 + i];
          rl[m][i] = 1.0f / (p[0] + p[1] + p[2] + p[3]);
        }
    }

    STAGE(0, 0);
    __syncthreads();                       // tile 0 resident
    int cur = 0;
    for (int t = 0; t < NTILES; ++t) {
      if (t + 1 < NTILES) STAGE(cur ^ 1, t + 1);   // prefetch next tile

      // ---- B fragments from LDS (swizzled read) ----
      const char* rb = rbase + cur * 32768;
      short8 bfrag[8];
      #pragma unroll
      for (int dblk = 0; dblk < 8; ++dblk)
        bfrag[dblk] = *(const short8*)(rb + dsoff[dblk]);

      f32x4 acc[4];
      #pragma unroll
      for (int m = 0; m < 4; ++m) acc[m] = f32x4{0.f, 0.f, 0.f, 0.f};
      __builtin_amdgcn_s_setprio(1);
      #pragma unroll
      for (int m = 0; m < 4; ++m)
        #pragma unroll
        for (int dblk = 0; dblk < 8; ++dblk)
          acc[m] = __builtin_amdgcn_mfma_f32_16x16x32_bf16(a_frag[m][dblk], bfrag[dblk], acc[m], 0, 0, 0);
      __builtin_amdgcn_s_setprio(0);

      if (pass == 0) {
        #pragma unroll
        for (int m = 0; m < 4; ++m)
          #pragma unroll
          for (int i = 0; i < 4; ++i)
            l_part[m][i] += __expf(acc[m][i] * SCALE);
      } else {
        float cs = 0.f;
        #pragma unroll
        for (int m = 0; m < 4; ++m)
          #pragma unroll
          for (int i = 0; i < 4; ++i)
            cs += __expf(acc[m][i] * SCALE) * rl[m][i];
        cs += __shfl_xor(cs, 16);    // sum over the wave's 64 q-rows
        cs += __shfl_xor(cs, 32);
        if (lg == 0)
          atomicAdd(&w[(size_t)b * NS + t * TK + wid * 16 + lr], cs);
      }
      __syncthreads();               // tile t+1 resident for next iter
      cur ^= 1;
    }
  }
}

__global__ void out_kernel(const float* __restrict__ x, const float* __restrict__ w,
                           float* __restrict__ out) {
  const int b  = blockIdx.x & 7;
  const int kc = blockIdx.x >> 3;
  const int d  = threadIdx.x;
  const int k0 = kc * 128;
  const float* xbp = x + ((size_t)b * NS + k0) * ND;
  const float* wb  = w + (size_t)b * NS + k0;
  float acc = 0.f;
  #pragma unroll 8
  for (int k = 0; k < 128; ++k)
    acc += wb[k] * xbp[(size_t)k * ND + d];
  atomicAdd(&out[b * ND + d], acc);
}

extern "C" void kernel_launch(void* const* d_in, const int* in_sizes, int n_in,
                              void* d_out, int out_size, void* d_ws, size_t ws_size,
                              hipStream_t stream) {
  const float* x    = (const float*)d_in[0];
  const float* mask = (const float*)d_in[1];
  float* w = (float*)d_ws;
  const size_t W_BYTES   = (size_t)NB * NS * sizeof(float);        // 128 KB
  const size_t XBF_BYTES = (size_t)NB * NS * ND * sizeof(short);   // 16 MB
  short* xbf = nullptr;
  if (ws_size >= W_BYTES + XBF_BYTES)
    xbf = (short*)((char*)d_ws + W_BYTES);

  hipMemsetAsync(d_ws, 0, W_BYTES, stream);
  hipMemsetAsync(d_out, 0, (size_t)out_size * sizeof(float), stream);

  if (xbf)
    cvt_swz_kernel<<<(NB * NS * 32) / 256, 256, 0, stream>>>(x, xbf);

  attn_colsum_kernel<<<NB * (NS / TQ), NTHR, 0, stream>>>(x, mask, xbf, w);
  out_kernel<<<NB * (NS / 128), 256, 0, stream>>>(x, w, (float*)d_out);
}